// Round 11
// baseline (223.564 us; speedup 1.0000x reference)
//
#include <hip/hip_runtime.h>

typedef __attribute__((ext_vector_type(8))) short short8;
typedef __attribute__((ext_vector_type(4))) float f32x4;
typedef __attribute__((ext_vector_type(4))) unsigned short us4;
typedef __attribute__((ext_vector_type(8))) unsigned short us8;

constexpr int Bb = 64, Nn = 2048, CI = 64, CO = 64, KK = 3, DE = 10;
constexpr int NW = Bb * CI;          // 4096
constexpr int WPSZ = KK * CI * CO;   // 12288

__device__ __forceinline__ unsigned short f2bf(float f) {
  unsigned u = __float_as_uint(f);
  u += 0x7fff + ((u >> 16) & 1);   // RNE
  return (unsigned short)(u >> 16);
}
__device__ __forceinline__ float bf2f(unsigned short h) {
  return __uint_as_float(((unsigned)h) << 16);
}
__device__ __forceinline__ void gl2lds16(const void* g, void* l) {
  __builtin_amdgcn_global_load_lds(
      (const __attribute__((address_space(1))) void*)g,
      (__attribute__((address_space(3))) void*)l, 16, 0, 0);
}

// ---------------------------------------------------------------------------
// K1 prep (3 ranges):
//   0..2047    supports rows: S = softmax(relu(E E^T)) -> bf16
//              (R11: wave-shuffle reductions, 2 syncs instead of 16)
//   2048..4095 x transpose tiles: Xrow + XT (bf16)
//   4096..4215 folded weight pool: Wpf[d][c][i][o] bf16
// ---------------------------------------------------------------------------
__global__ __launch_bounds__(256) void prep_kernel(
    const float* __restrict__ E, unsigned short* __restrict__ S,
    const float* __restrict__ x, unsigned short* __restrict__ Xrow,
    unsigned short* __restrict__ XT, const float* __restrict__ Wp,
    unsigned short* __restrict__ Wpf) {
  __shared__ float sh[5376];   // staging 0..5119 | redM 5120..5123 | redS 5128..5131
  const int bid = blockIdx.x, t = threadIdx.x;

  if (bid < 2048) {
    const int n = bid;
    const int lane = t & 63, wv = t >> 6;
    float emb[DE];
#pragma unroll
    for (int d = 0; d < DE; d++) emb[d] = E[n * DE + d];

    float v[8];
    for (int h = 0; h < 4; h++) {        // stage rows [512h, 512h+512)
      __syncthreads();
      const float* src = E + (size_t)(512 * DE) * h;
#pragma unroll
      for (int q = 0; q < 5; q++) {
        const int idx = t + q * 256;     // 1280 float4s = 5120 floats
        *(float4*)&sh[idx * 4] = *(const float4*)(src + idx * 4);
      }
      __syncthreads();
#pragma unroll
      for (int jj = 0; jj < 2; jj++) {
        const int lm = t + jj * 256;
        const float2* er = (const float2*)&sh[lm * 10];
        float dot = 0.f;
#pragma unroll
        for (int p = 0; p < 5; p++) {
          const float2 e2 = er[p];
          dot += emb[2 * p] * e2.x + emb[2 * p + 1] * e2.y;
        }
        v[h * 2 + jj] = fmaxf(dot, 0.f);
      }
    }

    float r = -1e30f;
#pragma unroll
    for (int j = 0; j < 8; j++) r = fmaxf(r, v[j]);
#pragma unroll
    for (int off = 32; off; off >>= 1) r = fmaxf(r, __shfl_xor(r, off));
    if (lane == 0) sh[5120 + wv] = r;
    __syncthreads();
    const float rowmax = fmaxf(fmaxf(sh[5120], sh[5121]), fmaxf(sh[5122], sh[5123]));

    float lsum = 0.f;
#pragma unroll
    for (int j = 0; j < 8; j++) { v[j] = __expf(v[j] - rowmax); lsum += v[j]; }
#pragma unroll
    for (int off = 32; off; off >>= 1) lsum += __shfl_xor(lsum, off);
    if (lane == 0) sh[5128 + wv] = lsum;
    __syncthreads();
    const float inv = 1.f / (sh[5128] + sh[5129] + sh[5130] + sh[5131]);
#pragma unroll
    for (int j = 0; j < 8; j++) S[(size_t)n * Nn + t + j * 256] = f2bf(v[j] * inv);
  } else if (bid < 4096) {
    const int id = bid - 2048;
    const int b = id & 63, n0 = (id >> 6) * 64;
    const int i4 = (t & 15) * 4;
#pragma unroll
    for (int j = 0; j < 4; j++) {
      const int r = j * 16 + (t >> 4);
      const float4 v =
          *(const float4*)(x + (size_t)b * (Nn * CI) + (size_t)(n0 + r) * CI + i4);
      us4 o; o.x = f2bf(v.x); o.y = f2bf(v.y); o.z = f2bf(v.z); o.w = f2bf(v.w);
      *(us4*)(Xrow + (size_t)(n0 + r) * NW + b * CI + i4) = o;
      sh[r * 65 + i4 + 0] = v.x; sh[r * 65 + i4 + 1] = v.y;
      sh[r * 65 + i4 + 2] = v.z; sh[r * 65 + i4 + 3] = v.w;
    }
    __syncthreads();
    const int i = t >> 2, c0 = (t & 3) * 16;
    us8 p0, p1;
#pragma unroll
    for (int j = 0; j < 8; j++) p0[j] = f2bf(sh[(c0 + j) * 65 + i]);
#pragma unroll
    for (int j = 0; j < 8; j++) p1[j] = f2bf(sh[(c0 + 8 + j) * 65 + i]);
    unsigned short* dst = XT + (size_t)(b * CI + i) * Nn + n0 + c0;
    *(us8*)(dst) = p0;
    *(us8*)(dst + 8) = p1;
  } else {
    const int e4 = ((bid - 4096) * 256 + t) * 4;
    const int d = e4 / WPSZ;
    const int r = e4 - d * WPSZ;          // c*4096 + i*64 + o
    const int c = r >> 12, io = r & 4095;
    float4 v = *(const float4*)(Wp + (size_t)d * WPSZ + c * 4096 + io);
    if (c == 0) {
      const float4 w2 = *(const float4*)(Wp + (size_t)d * WPSZ + 2 * 4096 + io);
      v.x -= w2.x; v.y -= w2.y; v.z -= w2.z; v.w -= w2.w;
    } else if (c == 2) {
      v.x *= 2.f; v.y *= 2.f; v.z *= 2.f; v.w *= 2.f;
    }
    us4 o; o.x = f2bf(v.x); o.y = f2bf(v.y); o.z = f2bf(v.z); o.w = f2bf(v.w);
    *(us4*)(Wpf + e4) = o;
  }
}

// ---------------------------------------------------------------------------
// K3: MFMA GEMM (R8-verified datapath). R11: grid swapped to (16 m, 64 n) so
// XCD = m_tile%8 -> per-XCD A(S) L2 footprint 1 MB (was 8.4 MB).
// mode 0: Crow + Ct^T; mode 1: Crow only.
// ---------------------------------------------------------------------------
__global__ __launch_bounds__(256) void mfma_gemm(
    const unsigned short* __restrict__ A, const unsigned short* __restrict__ Bt,
    unsigned short* __restrict__ Crow, unsigned short* __restrict__ Ct, int mode) {
  __shared__ unsigned short sm[12288];  // As 128x64, Bs 64x64
  unsigned short* As = sm;
  unsigned short* Bs = sm + 8192;
  const int t = threadIdx.x, lane = t & 63, wave = t >> 6;
  const int m0 = blockIdx.x * 128, n0 = blockIdx.y * 64;   // R11 swap
  const int wm = (wave & 1) * 64, wn = (wave >> 1) * 32;
  const int lr = lane & 15, lq = lane >> 4;

  f32x4 acc[4][2] = {};
  const int srow = lane >> 3;
  const int schunk = (lane & 7) ^ srow;

  for (int k0 = 0; k0 < 2048; k0 += 64) {
    __syncthreads();
#pragma unroll
    for (int j = 0; j < 4; j++) {
      const int r0 = (wave * 4 + j) * 8;
      gl2lds16(A + (size_t)(m0 + r0 + srow) * 2048 + k0 + schunk * 8, As + r0 * 64);
    }
#pragma unroll
    for (int j = 0; j < 2; j++) {
      const int r0 = (wave * 2 + j) * 8;
      gl2lds16(Bt + (size_t)(n0 + r0 + srow) * 2048 + k0 + schunk * 8, Bs + r0 * 64);
    }
    __syncthreads();
#pragma unroll
    for (int ks = 0; ks < 2; ks++) {
      short8 af[4], bfr[2];
#pragma unroll
      for (int i = 0; i < 4; i++) {
        const int m = wm + i * 16 + lr;
        const int slot = (ks * 4 + lq) ^ (m & 7);
        af[i] = *(const short8*)(As + m * 64 + slot * 8);
      }
#pragma unroll
      for (int j = 0; j < 2; j++) {
        const int n = wn + j * 16 + lr;
        const int slot = (ks * 4 + lq) ^ (n & 7);
        bfr[j] = *(const short8*)(Bs + n * 64 + slot * 8);
      }
#pragma unroll
      for (int i = 0; i < 4; i++)
#pragma unroll
        for (int j = 0; j < 2; j++)
          acc[i][j] = __builtin_amdgcn_mfma_f32_16x16x32_bf16(af[i], bfr[j], acc[i][j], 0, 0, 0);
    }
  }

  __syncthreads();
#pragma unroll
  for (int i = 0; i < 4; i++) {
#pragma unroll
    for (int r = 0; r < 4; r++) {
      const int m = wm + i * 16 + lq * 4 + r;
      const int sw = (m & 7) ^ ((m >> 3) & 7);
#pragma unroll
      for (int j = 0; j < 2; j++) {
        const int n = wn + j * 16 + lr;
        sm[m * 64 + (((n >> 3) ^ sw) * 8) + (n & 7)] = f2bf(acc[i][j][r]);
      }
    }
  }
  __syncthreads();

  {
    const int rr = t >> 3, cc = (t & 7) * 8;
#pragma unroll
    for (int p = 0; p < 4; p++) {
      const int m = p * 32 + rr;
      const int slot = (cc >> 3) ^ (m & 7) ^ ((m >> 3) & 7);
      const us8 v = *(const us8*)(sm + m * 64 + slot * 8);
      *(us8*)(Crow + (size_t)(m0 + m) * NW + n0 + cc) = v;
    }
  }
  if (mode == 0) {
    const int mc = (t & 15) * 8;
#pragma unroll
    for (int p = 0; p < 4; p++) {
      const int n = p * 16 + (t >> 4);
      us8 v;
#pragma unroll
      for (int q = 0; q < 8; q++) {
        const int m = mc + q;
        v[q] = sm[m * 64 + (((n >> 3) ^ (m & 7) ^ ((m >> 3) & 7)) * 8) + (n & 7)];
      }
      *(us8*)(Ct + (size_t)(n0 + n) * 2048 + m0 + mc) = v;
    }
  }
}

// ---------------------------------------------------------------------------
// K4 (R9-verified gen+MFMA; R11: float4 store epilogue via LDS bounce).
// out = X(W0-W2) + XG1*W1 + Y*2W2  (fold done in prep).
// ---------------------------------------------------------------------------
__global__ __launch_bounds__(256) void out_kernel(
    const unsigned short* __restrict__ Xrow, const unsigned short* __restrict__ XG1,
    const unsigned short* __restrict__ Yr, const float* __restrict__ E,
    const unsigned short* __restrict__ Wpf, const float* __restrict__ bp,
    float* __restrict__ out) {
  __shared__ unsigned short Wt[KK * CO * 64];  // 24 KB; reused as fp32 64x68 tile
  __shared__ unsigned short Al[KK * Bb * CI];  // 24 KB
  __shared__ float biasl[CO];

  const int n = blockIdx.x, t = threadIdx.x, lane = t & 63, wave = t >> 6;

  // --- activation DMA first (overlaps weight gen) ---
  const unsigned short* srcs[KK] = {Xrow + (size_t)n * NW, XG1 + (size_t)n * NW,
                                    Yr + (size_t)n * NW};
  const int srow = lane >> 3;
  const int schunk = (lane & 7) ^ srow;
#pragma unroll
  for (int j = 0; j < 6; j++) {
    const int r0 = (wave * 6 + j) * 8;
    const int c = r0 >> 6, b0 = r0 & 63;
    gl2lds16(srcs[c] + (b0 + srow) * 64 + schunk * 8, Al + r0 * 64);
  }

  // --- weight gen from folded bf16 pool ---
  float emb[DE];
#pragma unroll
  for (int d = 0; d < DE; d++) emb[d] = E[n * DE + d];

  const int o8 = (t & 7) * 8;
#pragma unroll
  for (int j = 0; j < 6; j++) {
    const int c = j >> 1;
    const int i = (j & 1) * 32 + (t >> 3);
    float w[8] = {};
#pragma unroll
    for (int d = 0; d < DE; d++) {
      const us8 wp = *(const us8*)(Wpf + (size_t)d * WPSZ + c * 4096 + i * 64 + o8);
#pragma unroll
      for (int q = 0; q < 8; q++) w[q] += emb[d] * bf2f(wp[q]);
    }
    const int chunk = i >> 3, ilo = i & 7;
#pragma unroll
    for (int q = 0; q < 8; q++) {
      const int o = o8 + q;
      Wt[(c * 64 + o) * 64 + ((chunk ^ (o & 7)) * 8) + ilo] = f2bf(w[q]);
    }
  }
  if (t < CO) {
    float bsum = 0.f;
#pragma unroll
    for (int d = 0; d < DE; d++) bsum += emb[d] * bp[d * CO + t];
    biasl[t] = bsum;
  }
  __syncthreads();   // drains DMA (vmcnt) + LDS writes

  // --- MFMA phase ---
  const int lr = lane & 15, lq = lane >> 4;
  f32x4 acc[4] = {};
#pragma unroll
  for (int kt = 0; kt < 6; kt++) {
    const int c = kt >> 1;
    const int chunk = (kt & 1) * 4 + lq;
    const int o = wave * 16 + lr;
    const short8 bfrag =
        *(const short8*)(Wt + (c * 64 + o) * 64 + (chunk ^ (o & 7)) * 8);
#pragma unroll
    for (int mt = 0; mt < 4; mt++) {
      const int b = mt * 16 + lr;
      const short8 afrag =
          *(const short8*)(Al + (c * 64 + b) * 64 + (chunk ^ (b & 7)) * 8);
      acc[mt] = __builtin_amdgcn_mfma_f32_16x16x32_bf16(afrag, bfrag, acc[mt], 0, 0, 0);
    }
  }

  // --- R11 epilogue: acc -> fp32 LDS tile (pitch 68, 2-way max) -> float4 stores
  __syncthreads();                       // Wt/Al reads complete
  float* F = (float*)Wt;                 // 64x68 fp32 = 17408 B (fits 24 KB)
#pragma unroll
  for (int mt = 0; mt < 4; mt++)
#pragma unroll
    for (int r = 0; r < 4; r++)
      F[(mt * 16 + lq * 4 + r) * 68 + wave * 16 + lr] = acc[mt][r];
  __syncthreads();

  const int bo = t >> 4, o4 = (t & 15) * 4;
#pragma unroll
  for (int mt = 0; mt < 4; mt++) {
    const int b = mt * 16 + bo;
    float4 v = *(const float4*)&F[b * 68 + o4];
    v.x += biasl[o4 + 0]; v.y += biasl[o4 + 1];
    v.z += biasl[o4 + 2]; v.w += biasl[o4 + 3];
    *(float4*)(out + (size_t)b * (Nn * CO) + (size_t)n * CO + o4) = v;
  }
}

// ---------------------------------------------------------------------------
extern "C" void kernel_launch(void* const* d_in, const int* in_sizes, int n_in,
                              void* d_out, int out_size, void* d_ws,
                              size_t ws_size, hipStream_t stream) {
  const float* x  = (const float*)d_in[0];
  const float* E  = (const float*)d_in[1];
  const float* Wp = (const float*)d_in[2];
  const float* bp = (const float*)d_in[3];
  float* out = (float*)d_out;

  unsigned short* ws   = (unsigned short*)d_ws;
  unsigned short* Xrow = ws;                              // [2048][4096]
  unsigned short* XG1r = Xrow + (size_t)Nn * NW;          // [2048][4096]
  unsigned short* Yr   = XG1r + (size_t)Nn * NW;          // [2048][4096]
  unsigned short* S    = Yr   + (size_t)Nn * NW;          // [2048][2048]
  unsigned short* XT   = S    + (size_t)Nn * Nn;          // [4096][2048]
  unsigned short* XG1T = XT   + (size_t)NW * Nn;          // [4096][2048]
  unsigned short* Wpf  = XG1T + (size_t)NW * Nn;          // [10][12288] -> 88.25 MB

  prep_kernel<<<4216, 256, 0, stream>>>(E, S, x, Xrow, XT, Wp, Wpf);

  dim3 g(Nn / 128, NW / 64);  // (16, 64): XCD = m_tile%8
  mfma_gemm<<<g, 256, 0, stream>>>(S, XT,   XG1r, XG1T, 0);     // XG1 = S@X
  mfma_gemm<<<g, 256, 0, stream>>>(S, XG1T, Yr,   nullptr, 1);  // Y = S@XG1

  out_kernel<<<Nn, 256, 0, stream>>>(Xrow, XG1r, Yr, E, Wpf, bp, out);
}

// Round 12
// 207.410 us; speedup vs baseline: 1.0779x; 1.0779x over previous
//
#include <hip/hip_runtime.h>

typedef __attribute__((ext_vector_type(8))) short short8;
typedef __attribute__((ext_vector_type(4))) float f32x4;
typedef __attribute__((ext_vector_type(4))) unsigned short us4;
typedef __attribute__((ext_vector_type(8))) unsigned short us8;

constexpr int Bb = 64, Nn = 2048, CI = 64, CO = 64, KK = 3, DE = 10;
constexpr int NW = Bb * CI;          // 4096
constexpr int WPSZ = KK * CI * CO;   // 12288

__device__ __forceinline__ unsigned short f2bf(float f) {
  unsigned u = __float_as_uint(f);
  u += 0x7fff + ((u >> 16) & 1);   // RNE
  return (unsigned short)(u >> 16);
}
__device__ __forceinline__ float bf2f(unsigned short h) {
  return __uint_as_float(((unsigned)h) << 16);
}
__device__ __forceinline__ void gl2lds16(const void* g, void* l) {
  __builtin_amdgcn_global_load_lds(
      (const __attribute__((address_space(1))) void*)g,
      (__attribute__((address_space(3))) void*)l, 16, 0, 0);
}

// ---------------------------------------------------------------------------
// K1 prep (3 ranges):
//   0..2047    supports rows: S = softmax(relu(E E^T)) -> bf16 (shuffle red.)
//   2048..4095 x transpose tiles: Xrow + XT (bf16)
//   4096..4215 folded weight pool: Wpf[d][c][i][o] bf16
// ---------------------------------------------------------------------------
__global__ __launch_bounds__(256) void prep_kernel(
    const float* __restrict__ E, unsigned short* __restrict__ S,
    const float* __restrict__ x, unsigned short* __restrict__ Xrow,
    unsigned short* __restrict__ XT, const float* __restrict__ Wp,
    unsigned short* __restrict__ Wpf) {
  __shared__ float sh[5376];   // staging 0..5119 | redM 5120..5123 | redS 5128..5131
  const int bid = blockIdx.x, t = threadIdx.x;

  if (bid < 2048) {
    const int n = bid;
    const int lane = t & 63, wv = t >> 6;
    float emb[DE];
#pragma unroll
    for (int d = 0; d < DE; d++) emb[d] = E[n * DE + d];

    float v[8];
    for (int h = 0; h < 4; h++) {        // stage rows [512h, 512h+512)
      __syncthreads();
      const float* src = E + (size_t)(512 * DE) * h;
#pragma unroll
      for (int q = 0; q < 5; q++) {
        const int idx = t + q * 256;     // 1280 float4s = 5120 floats
        *(float4*)&sh[idx * 4] = *(const float4*)(src + idx * 4);
      }
      __syncthreads();
#pragma unroll
      for (int jj = 0; jj < 2; jj++) {
        const int lm = t + jj * 256;
        const float2* er = (const float2*)&sh[lm * 10];
        float dot = 0.f;
#pragma unroll
        for (int p = 0; p < 5; p++) {
          const float2 e2 = er[p];
          dot += emb[2 * p] * e2.x + emb[2 * p + 1] * e2.y;
        }
        v[h * 2 + jj] = fmaxf(dot, 0.f);
      }
    }

    float r = -1e30f;
#pragma unroll
    for (int j = 0; j < 8; j++) r = fmaxf(r, v[j]);
#pragma unroll
    for (int off = 32; off; off >>= 1) r = fmaxf(r, __shfl_xor(r, off));
    if (lane == 0) sh[5120 + wv] = r;
    __syncthreads();
    const float rowmax = fmaxf(fmaxf(sh[5120], sh[5121]), fmaxf(sh[5122], sh[5123]));

    float lsum = 0.f;
#pragma unroll
    for (int j = 0; j < 8; j++) { v[j] = __expf(v[j] - rowmax); lsum += v[j]; }
#pragma unroll
    for (int off = 32; off; off >>= 1) lsum += __shfl_xor(lsum, off);
    if (lane == 0) sh[5128 + wv] = lsum;
    __syncthreads();
    const float inv = 1.f / (sh[5128] + sh[5129] + sh[5130] + sh[5131]);
#pragma unroll
    for (int j = 0; j < 8; j++) S[(size_t)n * Nn + t + j * 256] = f2bf(v[j] * inv);
  } else if (bid < 4096) {
    const int id = bid - 2048;
    const int b = id & 63, n0 = (id >> 6) * 64;
    const int i4 = (t & 15) * 4;
#pragma unroll
    for (int j = 0; j < 4; j++) {
      const int r = j * 16 + (t >> 4);
      const float4 v =
          *(const float4*)(x + (size_t)b * (Nn * CI) + (size_t)(n0 + r) * CI + i4);
      us4 o; o.x = f2bf(v.x); o.y = f2bf(v.y); o.z = f2bf(v.z); o.w = f2bf(v.w);
      *(us4*)(Xrow + (size_t)(n0 + r) * NW + b * CI + i4) = o;
      sh[r * 65 + i4 + 0] = v.x; sh[r * 65 + i4 + 1] = v.y;
      sh[r * 65 + i4 + 2] = v.z; sh[r * 65 + i4 + 3] = v.w;
    }
    __syncthreads();
    const int i = t >> 2, c0 = (t & 3) * 16;
    us8 p0, p1;
#pragma unroll
    for (int j = 0; j < 8; j++) p0[j] = f2bf(sh[(c0 + j) * 65 + i]);
#pragma unroll
    for (int j = 0; j < 8; j++) p1[j] = f2bf(sh[(c0 + 8 + j) * 65 + i]);
    unsigned short* dst = XT + (size_t)(b * CI + i) * Nn + n0 + c0;
    *(us8*)(dst) = p0;
    *(us8*)(dst + 8) = p1;
  } else {
    const int e4 = ((bid - 4096) * 256 + t) * 4;
    const int d = e4 / WPSZ;
    const int r = e4 - d * WPSZ;          // c*4096 + i*64 + o
    const int c = r >> 12, io = r & 4095;
    float4 v = *(const float4*)(Wp + (size_t)d * WPSZ + c * 4096 + io);
    if (c == 0) {
      const float4 w2 = *(const float4*)(Wp + (size_t)d * WPSZ + 2 * 4096 + io);
      v.x -= w2.x; v.y -= w2.y; v.z -= w2.z; v.w -= w2.w;
    } else if (c == 2) {
      v.x *= 2.f; v.y *= 2.f; v.z *= 2.f; v.w *= 2.f;
    }
    us4 o; o.x = f2bf(v.x); o.y = f2bf(v.y); o.z = f2bf(v.z); o.w = f2bf(v.w);
    *(us4*)(Wpf + e4) = o;
  }
}

// ---------------------------------------------------------------------------
// K3: MFMA GEMM (R8/R10-verified datapath AND grid orientation).
// R12: grid reverted to (64 n, 16 m) — R11's swap doubled HBM fetch
// (42.5->70 MB): consecutive blocks must share the A-slice (same m-tile),
// which the original orientation provides.
// mode 0: Crow + Ct^T; mode 1: Crow only.
// ---------------------------------------------------------------------------
__global__ __launch_bounds__(256) void mfma_gemm(
    const unsigned short* __restrict__ A, const unsigned short* __restrict__ Bt,
    unsigned short* __restrict__ Crow, unsigned short* __restrict__ Ct, int mode) {
  __shared__ unsigned short sm[12288];  // As 128x64, Bs 64x64
  unsigned short* As = sm;
  unsigned short* Bs = sm + 8192;
  const int t = threadIdx.x, lane = t & 63, wave = t >> 6;
  const int n0 = blockIdx.x * 64, m0 = blockIdx.y * 128;   // R10 orientation
  const int wm = (wave & 1) * 64, wn = (wave >> 1) * 32;
  const int lr = lane & 15, lq = lane >> 4;

  f32x4 acc[4][2] = {};
  const int srow = lane >> 3;
  const int schunk = (lane & 7) ^ srow;

  for (int k0 = 0; k0 < 2048; k0 += 64) {
    __syncthreads();
#pragma unroll
    for (int j = 0; j < 4; j++) {
      const int r0 = (wave * 4 + j) * 8;
      gl2lds16(A + (size_t)(m0 + r0 + srow) * 2048 + k0 + schunk * 8, As + r0 * 64);
    }
#pragma unroll
    for (int j = 0; j < 2; j++) {
      const int r0 = (wave * 2 + j) * 8;
      gl2lds16(Bt + (size_t)(n0 + r0 + srow) * 2048 + k0 + schunk * 8, Bs + r0 * 64);
    }
    __syncthreads();
#pragma unroll
    for (int ks = 0; ks < 2; ks++) {
      short8 af[4], bfr[2];
#pragma unroll
      for (int i = 0; i < 4; i++) {
        const int m = wm + i * 16 + lr;
        const int slot = (ks * 4 + lq) ^ (m & 7);
        af[i] = *(const short8*)(As + m * 64 + slot * 8);
      }
#pragma unroll
      for (int j = 0; j < 2; j++) {
        const int n = wn + j * 16 + lr;
        const int slot = (ks * 4 + lq) ^ (n & 7);
        bfr[j] = *(const short8*)(Bs + n * 64 + slot * 8);
      }
#pragma unroll
      for (int i = 0; i < 4; i++)
#pragma unroll
        for (int j = 0; j < 2; j++)
          acc[i][j] = __builtin_amdgcn_mfma_f32_16x16x32_bf16(af[i], bfr[j], acc[i][j], 0, 0, 0);
    }
  }

  __syncthreads();
#pragma unroll
  for (int i = 0; i < 4; i++) {
#pragma unroll
    for (int r = 0; r < 4; r++) {
      const int m = wm + i * 16 + lq * 4 + r;
      const int sw = (m & 7) ^ ((m >> 3) & 7);
#pragma unroll
      for (int j = 0; j < 2; j++) {
        const int n = wn + j * 16 + lr;
        sm[m * 64 + (((n >> 3) ^ sw) * 8) + (n & 7)] = f2bf(acc[i][j][r]);
      }
    }
  }
  __syncthreads();

  {
    const int rr = t >> 3, cc = (t & 7) * 8;
#pragma unroll
    for (int p = 0; p < 4; p++) {
      const int m = p * 32 + rr;
      const int slot = (cc >> 3) ^ (m & 7) ^ ((m >> 3) & 7);
      const us8 v = *(const us8*)(sm + m * 64 + slot * 8);
      *(us8*)(Crow + (size_t)(m0 + m) * NW + n0 + cc) = v;
    }
  }
  if (mode == 0) {
    const int mc = (t & 15) * 8;
#pragma unroll
    for (int p = 0; p < 4; p++) {
      const int n = p * 16 + (t >> 4);
      us8 v;
#pragma unroll
      for (int q = 0; q < 8; q++) {
        const int m = mc + q;
        v[q] = sm[m * 64 + (((n >> 3) ^ (m & 7) ^ ((m >> 3) & 7)) * 8) + (n & 7)];
      }
      *(us8*)(Ct + (size_t)(n0 + n) * 2048 + m0 + mc) = v;
    }
  }
}

// ---------------------------------------------------------------------------
// K4 (R9-verified gen+MFMA; R11 float4-store epilogue kept for attribution).
// out = X(W0-W2) + XG1*W1 + Y*2W2  (fold done in prep).
// ---------------------------------------------------------------------------
__global__ __launch_bounds__(256) void out_kernel(
    const unsigned short* __restrict__ Xrow, const unsigned short* __restrict__ XG1,
    const unsigned short* __restrict__ Yr, const float* __restrict__ E,
    const unsigned short* __restrict__ Wpf, const float* __restrict__ bp,
    float* __restrict__ out) {
  __shared__ unsigned short Wt[KK * CO * 64];  // 24 KB; reused as fp32 64x68 tile
  __shared__ unsigned short Al[KK * Bb * CI];  // 24 KB
  __shared__ float biasl[CO];

  const int n = blockIdx.x, t = threadIdx.x, lane = t & 63, wave = t >> 6;

  // --- activation DMA first (overlaps weight gen) ---
  const unsigned short* srcs[KK] = {Xrow + (size_t)n * NW, XG1 + (size_t)n * NW,
                                    Yr + (size_t)n * NW};
  const int srow = lane >> 3;
  const int schunk = (lane & 7) ^ srow;
#pragma unroll
  for (int j = 0; j < 6; j++) {
    const int r0 = (wave * 6 + j) * 8;
    const int c = r0 >> 6, b0 = r0 & 63;
    gl2lds16(srcs[c] + (b0 + srow) * 64 + schunk * 8, Al + r0 * 64);
  }

  // --- weight gen from folded bf16 pool ---
  float emb[DE];
#pragma unroll
  for (int d = 0; d < DE; d++) emb[d] = E[n * DE + d];

  const int o8 = (t & 7) * 8;
#pragma unroll
  for (int j = 0; j < 6; j++) {
    const int c = j >> 1;
    const int i = (j & 1) * 32 + (t >> 3);
    float w[8] = {};
#pragma unroll
    for (int d = 0; d < DE; d++) {
      const us8 wp = *(const us8*)(Wpf + (size_t)d * WPSZ + c * 4096 + i * 64 + o8);
#pragma unroll
      for (int q = 0; q < 8; q++) w[q] += emb[d] * bf2f(wp[q]);
    }
    const int chunk = i >> 3, ilo = i & 7;
#pragma unroll
    for (int q = 0; q < 8; q++) {
      const int o = o8 + q;
      Wt[(c * 64 + o) * 64 + ((chunk ^ (o & 7)) * 8) + ilo] = f2bf(w[q]);
    }
  }
  if (t < CO) {
    float bsum = 0.f;
#pragma unroll
    for (int d = 0; d < DE; d++) bsum += emb[d] * bp[d * CO + t];
    biasl[t] = bsum;
  }
  __syncthreads();   // drains DMA (vmcnt) + LDS writes

  // --- MFMA phase ---
  const int lr = lane & 15, lq = lane >> 4;
  f32x4 acc[4] = {};
#pragma unroll
  for (int kt = 0; kt < 6; kt++) {
    const int c = kt >> 1;
    const int chunk = (kt & 1) * 4 + lq;
    const int o = wave * 16 + lr;
    const short8 bfrag =
        *(const short8*)(Wt + (c * 64 + o) * 64 + (chunk ^ (o & 7)) * 8);
#pragma unroll
    for (int mt = 0; mt < 4; mt++) {
      const int b = mt * 16 + lr;
      const short8 afrag =
          *(const short8*)(Al + (c * 64 + b) * 64 + (chunk ^ (b & 7)) * 8);
      acc[mt] = __builtin_amdgcn_mfma_f32_16x16x32_bf16(afrag, bfrag, acc[mt], 0, 0, 0);
    }
  }

  // --- float4-store epilogue via LDS bounce ---
  __syncthreads();                       // Wt/Al reads complete
  float* F = (float*)Wt;                 // 64x68 fp32 = 17408 B (fits 24 KB)
#pragma unroll
  for (int mt = 0; mt < 4; mt++)
#pragma unroll
    for (int r = 0; r < 4; r++)
      F[(mt * 16 + lq * 4 + r) * 68 + wave * 16 + lr] = acc[mt][r];
  __syncthreads();

  const int bo = t >> 4, o4 = (t & 15) * 4;
#pragma unroll
  for (int mt = 0; mt < 4; mt++) {
    const int b = mt * 16 + bo;
    float4 v = *(const float4*)&F[b * 68 + o4];
    v.x += biasl[o4 + 0]; v.y += biasl[o4 + 1];
    v.z += biasl[o4 + 2]; v.w += biasl[o4 + 3];
    *(float4*)(out + (size_t)b * (Nn * CO) + (size_t)n * CO + o4) = v;
  }
}

// ---------------------------------------------------------------------------
extern "C" void kernel_launch(void* const* d_in, const int* in_sizes, int n_in,
                              void* d_out, int out_size, void* d_ws,
                              size_t ws_size, hipStream_t stream) {
  const float* x  = (const float*)d_in[0];
  const float* E  = (const float*)d_in[1];
  const float* Wp = (const float*)d_in[2];
  const float* bp = (const float*)d_in[3];
  float* out = (float*)d_out;

  unsigned short* ws   = (unsigned short*)d_ws;
  unsigned short* Xrow = ws;                              // [2048][4096]
  unsigned short* XG1r = Xrow + (size_t)Nn * NW;          // [2048][4096]
  unsigned short* Yr   = XG1r + (size_t)Nn * NW;          // [2048][4096]
  unsigned short* S    = Yr   + (size_t)Nn * NW;          // [2048][2048]
  unsigned short* XT   = S    + (size_t)Nn * Nn;          // [4096][2048]
  unsigned short* XG1T = XT   + (size_t)NW * Nn;          // [4096][2048]
  unsigned short* Wpf  = XG1T + (size_t)NW * Nn;          // [10][12288] -> 88.25 MB

  prep_kernel<<<4216, 256, 0, stream>>>(E, S, x, Xrow, XT, Wp, Wpf);

  dim3 g(NW / 64, Nn / 128);  // (64, 16): consecutive blocks share the A-slice
  mfma_gemm<<<g, 256, 0, stream>>>(S, XT,   XG1r, XG1T, 0);     // XG1 = S@X
  mfma_gemm<<<g, 256, 0, stream>>>(S, XG1T, Yr,   nullptr, 1);  // Y = S@XG1

  out_kernel<<<Nn, 256, 0, stream>>>(Xrow, XG1r, Yr, E, Wpf, bp, out);
}